// Round 15
// baseline (11801.126 us; speedup 1.0000x reference)
//
#include <hip/hip_runtime.h>

// AlphatRNN B=128,T=512,D=256,H=1024,L=2,O=1 — bf16 MFMA persistent kernel, R15.
// R15 = R14 (two pools, 10.3ms) with SLIMMED SYNC MACHINERY:
//  - wave-targeted polls: wave wv's K-eighth comes from producers wgl={wv,wv+8}
//    -> poll 2 flags, no WG-wide sync (asm memory clobber stops compiler
//    hoisting; HW issues a wave's VMEM in order).
//  - write-side WAR throttles owner-only (lanes 0-15 poll all 16, 1 epoch lag):
//    fB>=t (s0 parity), fC>=t-31 (h0 ring), fD>=t-1 (s1 parity).
//  - single-sync dual-plane reduce (skip-own packing, 56KB LDS); D's reduce-get
//    DEFERRED into C(t+1) (h1 only needed there) -> its sync merges with fD set.
//  - L1's fC window hides pD1 GEMM + next ring-h0 frag load.
// L0 = 2 syncs/step, L1 = 3 (was ~9). Dataflow/math identical to R14.

typedef unsigned short u16;
typedef unsigned long long u64;
typedef __attribute__((ext_vector_type(8))) short short8;
typedef __attribute__((ext_vector_type(4))) float f32x4;

#define NB   128
#define TT   512
#define DD   256
#define HH   1024
#define NTHR 512
#define SPAN (NB * HH)
#define RING 32
#define GS   16

// ---- ws layout (bytes) ----
#define S0_OFF  0u          // bf16 [2][128][1024] s0 parity
#define S1_OFF  524288u     // bf16 [2][128][1024] s1 parity
#define H0_OFF  1048576u    // bf16 [RING][128][1024] = 8 MB h0 ring
#define FL_OFF  9437184u    // fB/fC/fD: 3 x [8 mg][16 wgl] x 64 B = 24 KB
#define W_OFF   9486336u    // bf16 weights: 6x[1024][1024], then [1024][256]x2
#define NBIG    6291456u

__device__ __forceinline__ u16 f2bf(float f) {
    unsigned u = __builtin_bit_cast(unsigned, f);
    return (u16)((u + 0x7fffu + ((u >> 16) & 1u)) >> 16);
}
__device__ __forceinline__ u64 agent_load64(const u64* p) {
    return __hip_atomic_load(p, __ATOMIC_RELAXED, __HIP_MEMORY_SCOPE_AGENT);
}
__device__ __forceinline__ void agent_store64(u64* p, u64 v) {
    __hip_atomic_store(p, v, __ATOMIC_RELAXED, __HIP_MEMORY_SCOPE_AGENT);
}

// flag set: __syncthreads (precedes call) drains sc1 stores; tid0 releases.
__device__ __forceinline__ void flag_set(unsigned* f, int wgl, unsigned val, int tid)
{
    if (tid == 0)
        __hip_atomic_store(f + wgl * 16, val, __ATOMIC_RELEASE,
                           __HIP_MEMORY_SCOPE_AGENT);
}
// wave-targeted poll: this wave's K-eighth has exactly 2 producers {wv, wv+8}.
__device__ __forceinline__ void wait2(unsigned* f, int wv, unsigned val, int lane)
{
    if (lane < 2) {
        const int p = lane ? (wv + 8) : wv;
        while (__hip_atomic_load(f + p * 16, __ATOMIC_RELAXED,
                                 __HIP_MEMORY_SCOPE_AGENT) < val)
            __builtin_amdgcn_s_sleep(1);
    }
    asm volatile("" ::: "memory");   // no load hoisting past the poll
}
// owner-side write throttle: all 16 producers (lanes 0..15), no WG sync.
__device__ __forceinline__ void wait_all(unsigned* f, unsigned val, int lane)
{
    if (lane < GS) {
        while (__hip_atomic_load(f + lane * 16, __ATOMIC_RELAXED,
                                 __HIP_MEMORY_SCOPE_AGENT) < val)
            __builtin_amdgcn_s_sleep(1);
    }
    asm volatile("" ::: "memory");
}

// state frags, one K-EIGHTH (128 k): lane(lrow,lkg) reads row m0+lrow,
// k = wv*128 + s*32 + lkg*8, s=0..3. sc1 loads from a published span.
__device__ __forceinline__ void load_frags(short8* fr, const u16* base,
                                           int row, int wv, int lkg)
{
    const u16* sp = base + ((size_t)row << 10) + wv * 128 + lkg * 8;
    #pragma unroll
    for (int s = 0; s < 4; ++s) {
        union { short8 v; u64 q[2]; } u_;
        u_.q[0] = agent_load64((const u64*)(sp + s * 32));
        u_.q[1] = agent_load64((const u64*)(sp + s * 32 + 4));
        fr[s] = u_.v;
    }
}

// a[nt] += W[n0+nt*16+lrow, K-eighth] (x) S(frags), swapped operands
// (D rows = W rows = H-cols, D cols = batch). 16 mfma per call.
__device__ __forceinline__ void mm4(f32x4* a, const short8* fr, const u16* W,
                                    int n0, int lrow, int wv, int lkg)
{
    #pragma unroll
    for (int nt = 0; nt < 4; ++nt) {
        const u16* wp = W + ((size_t)(n0 + nt * 16 + lrow) << 10) + wv * 128 + lkg * 8;
        #pragma unroll
        for (int s = 0; s < 4; ++s)
            a[nt] = __builtin_amdgcn_mfma_f32_16x16x32_bf16(
                *(const short8*)(wp + s * 32), fr[s], a[nt], 0, 0, 0);
    }
}

// a[nt] += Wx[n0+nt*16+lrow, K-eighth of 256] (x) x_row(fp32->bf16), swapped.
__device__ __forceinline__ void mmx4(f32x4* a, const float* xrow, const u16* W,
                                     int n0, int lrow, int wv, int lkg)
{
    const float* p = xrow + wv * 32 + lkg * 8;
    float4 A = *(const float4*)p;
    float4 B = *(const float4*)(p + 4);
    short8 v;
    v[0]=(short)f2bf(A.x); v[1]=(short)f2bf(A.y); v[2]=(short)f2bf(A.z); v[3]=(short)f2bf(A.w);
    v[4]=(short)f2bf(B.x); v[5]=(short)f2bf(B.y); v[6]=(short)f2bf(B.z); v[7]=(short)f2bf(B.w);
    #pragma unroll
    for (int nt = 0; nt < 4; ++nt) {
        const u16* wp = W + ((size_t)(n0 + nt * 16 + lrow) << 8) + wv * 32 + lkg * 8;
        a[nt] = __builtin_amdgcn_mfma_f32_16x16x32_bf16(
            *(const short8*)wp, v, a[nt], 0, 0, 0);
    }
}

// skip-own reduce planes [q][comp][nt][7][lane] (56KB, conflict-free): wave wv
// writes nt!=wv at slot j=(wv<nt?wv:wv-1); owner wave nt keeps own in reg.
__device__ __forceinline__ void red_put(float (*red)[4][4][7][64], int q,
                                        const f32x4* a, int wv, int lane)
{
    #pragma unroll
    for (int nt = 0; nt < 4; ++nt) {
        if (nt != wv) {
            const int j = (wv < nt) ? wv : wv - 1;
            #pragma unroll
            for (int c = 0; c < 4; ++c) red[q][c][nt][j][lane] = a[nt][c];
        }
    }
}
__device__ __forceinline__ f32x4 red_get(float (*red)[4][4][7][64], int q,
                                         f32x4 own, int nt, int lane)
{
    #pragma unroll
    for (int j = 0; j < 7; ++j)
        #pragma unroll
        for (int c = 0; c < 4; ++c) own[c] += red[q][c][nt][j][lane];
    return own;
}

__device__ __forceinline__ u64 pack4(float a, float b, float c, float d)
{
    return (u64)f2bf(a) | ((u64)f2bf(b) << 16) | ((u64)f2bf(c) << 32)
         | ((u64)f2bf(d) << 48);
}

__global__ void conv_weights(const float* Uas0, const float* Whh0, const float* Wax1,
                             const float* Uas1, const float* Wih1, const float* Whh1,
                             const float* Wax0, const float* Wih0, u16* dst)
{
    for (size_t i = (size_t)blockIdx.x * blockDim.x + threadIdx.x; i < 6815744u;
         i += (size_t)gridDim.x * blockDim.x) {
        const float* src; size_t off;
        if (i < NBIG) {
            int seg = (int)(i >> 20); off = i & 1048575u;
            src = seg == 0 ? Uas0 : seg == 1 ? Whh0 : seg == 2 ? Wax1
                : seg == 3 ? Uas1 : seg == 4 ? Wih1 : Whh1;
        } else {
            size_t j = i - NBIG; off = j & 262143u;
            src = (j >> 18) ? Wih0 : Wax0;
        }
        dst[i] = f2bf(src[off]);
    }
}

extern "C" __global__ void __launch_bounds__(NTHR, 1)
alphat_mfma(const float* __restrict__ x,
            const u16* __restrict__ wUas0, const u16* __restrict__ wWhh0,
            const u16* __restrict__ wWax1, const u16* __restrict__ wUas1,
            const u16* __restrict__ wWih1, const u16* __restrict__ wWhh1,
            const u16* __restrict__ wWax0, const u16* __restrict__ wWih0,
            const float* __restrict__ ba0, const float* __restrict__ bh0,
            const float* __restrict__ ba1, const float* __restrict__ bh1,
            const float* __restrict__ fcW, const float* __restrict__ fcb,
            float* __restrict__ out,
            u16* s0b, u16* s1b, u16* h0r, unsigned* flags)
{
    __shared__ float red[2][4][4][7][64];   // 56 KB dual skip-own planes

    const int tid  = threadIdx.x;
    const int wv   = tid >> 6;              // K-eighth; waves 0-3 own n-tiles 0-3
    const int lane = tid & 63;
    const int lrow = lane & 15;
    const int lkg  = lane >> 4;

    const bool isL0 = (blockIdx.x < 128);
    const int wg  = isL0 ? blockIdx.x : (blockIdx.x - 128);
    const int ngg = (wg & 7) * 2 + ((wg >> 3) & 1);
    const int mg  = wg >> 4;
    const int wgl = wg & 15;
    const int m0  = mg * 16;
    const int n0  = ngg * 64;

    unsigned* fB = flags + (size_t)mg * 256;
    unsigned* fC = flags + 2048 + (size_t)mg * 256;
    unsigned* fD = flags + 4096 + (size_t)mg * 256;

    const int arow = m0 + lrow;
    const bool own = (wv < 4);
    const int nb   = n0 + (wv & 3) * 16 + lkg * 4;

    const f32x4 zf = {0.f, 0.f, 0.f, 0.f};
    const size_t HIDB = NB, SMOB = NB + 2 * (size_t)SPAN;

    if (isL0) {
        // ================== layer-0 pool: B chain (2 syncs/step) =============
        float4 vba0 = {0,0,0,0}, vbh0 = {0,0,0,0};
        if (own) { vba0 = *(const float4*)(ba0 + nb); vbh0 = *(const float4*)(bh0 + nb); }
        float h0l[4] = {0,0,0,0}, s0l[4] = {0,0,0,0};

        short8 frags[4];
        #pragma unroll
        for (int s = 0; s < 4; ++s)
            #pragma unroll
            for (int i = 0; i < 8; ++i) frags[s][i] = 0;
        const float* xbase = x + (size_t)arow * (TT * DD);
        f32x4 pBx[4], pAx[4];
        #pragma unroll
        for (int nt = 0; nt < 4; ++nt) { pBx[nt] = zf; pAx[nt] = zf; }
        mmx4(pBx, xbase + 0 * DD, wWih0, n0, lrow, wv, lkg);
        mmx4(pAx, xbase + 1 * DD, wWax0, n0, lrow, wv, lkg);

        for (int t = 0; t < TT; ++t) {
            u16* h0cur = h0r + (size_t)(t & (RING - 1)) * SPAN;
            u16* s0nxt = s0b + ((t + 1) & 1) * SPAN;

            // owner-side write throttles (1-epoch lagged, usually pre-satisfied):
            // s0 parity: B(t) overwrites s0(t-1); readers done iff fB >= t.
            // ring: h0cur slot held h0(t-32); readers done iff fC >= t-31.
            if (own) {
                wait_all(fB, (unsigned)t, lane);
                if (t >= RING) wait_all(fC, (unsigned)(t - RING + 1), lane);
            }

            f32x4 acc[4], pA[4];
            #pragma unroll
            for (int nt = 0; nt < 4; ++nt) { acc[nt] = pBx[nt]; pA[nt] = pAx[nt]; }
            mm4(acc, frags, wWhh0, n0, lrow, wv, lkg);
            mm4(pA,  frags, wUas0, n0, lrow, wv, lkg);

            red_put(red, 0, acc, wv, lane);
            red_put(red, 1, pA,  wv, lane);
            __syncthreads();                               // (1)
            if (own) {
                f32x4 accOwn = zf, pAOwn = zf;
                #pragma unroll
                for (int nt = 0; nt < 4; ++nt)
                    if (nt == wv) { accOwn = acc[nt]; pAOwn = pA[nt]; }
                f32x4 hsum = red_get(red, 0, accOwn, wv, lane);
                f32x4 asum = red_get(red, 1, pAOwn,  wv, lane);
                float hb[4];
                #pragma unroll
                for (int r = 0; r < 4; ++r) {
                    hb[r] = tanhf(hsum[r] + ((const float*)&vbh0)[r]);
                    h0l[r] = hb[r];
                }
                agent_store64((u64*)(h0cur + (size_t)(m0 + lrow) * HH + nb),
                              pack4(hb[0], hb[1], hb[2], hb[3]));
                if (t + 1 < TT) {
                    float sb[4];
                    #pragma unroll
                    for (int r = 0; r < 4; ++r) {
                        float al = 1.f / (1.f + __expf(-(asum[r] + ((const float*)&vba0)[r])));
                        sb[r] = al * hb[r] + (1.f - al) * s0l[r];
                        s0l[r] = sb[r];
                    }
                    agent_store64((u64*)(s0nxt + (size_t)(m0 + lrow) * HH + nb),
                                  pack4(sb[0], sb[1], sb[2], sb[3]));
                }
            }
            __syncthreads();                               // (2) drain stores
            flag_set(fB, wgl, (unsigned)(t + 1), tid);

            if (t + 1 < TT) {
                // fill the exchange window with next x partials
                #pragma unroll
                for (int nt = 0; nt < 4; ++nt) pBx[nt] = zf;
                mmx4(pBx, xbase + (size_t)(t + 1) * DD, wWih0, n0, lrow, wv, lkg);
                if (t + 2 < TT) {
                    #pragma unroll
                    for (int nt = 0; nt < 4; ++nt) pAx[nt] = zf;
                    mmx4(pAx, xbase + (size_t)(t + 2) * DD, wWax0, n0, lrow, wv, lkg);
                }
                wait2(fB, wv, (unsigned)(t + 1), lane);    // my 2 producers
                load_frags(frags, s0nxt, arow, wv, lkg);
            }
        }
        if (own) {
            const size_t o = (size_t)(m0 + lrow) * HH + nb;
            *(float4*)(out + HIDB + o) = make_float4(h0l[0], h0l[1], h0l[2], h0l[3]);
            *(float4*)(out + SMOB + o) = make_float4(s0l[0], s0l[1], s0l[2], s0l[3]);
        }
    } else {
        // ================== layer-1 pool: C+D (3 syncs/step) =================
        float4 vba1 = {0,0,0,0}, vbh1 = {0,0,0,0};
        if (own) { vba1 = *(const float4*)(ba1 + nb); vbh1 = *(const float4*)(bh1 + nb); }
        float h1l[4] = {0,0,0,0}, s1l[4] = {0,0,0,0};
        f32x4 pC1[4];
        #pragma unroll
        for (int nt = 0; nt < 4; ++nt) pC1[nt] = zf;
        f32x4 dOwn = zf;                       // own D partial (deferred reduce)

        // prologue: fh(0) from ring slot 0
        short8 fh[4];
        wait2(fB, wv, 1u, lane);
        load_frags(fh, h0r, arow, wv, lkg);

        for (int t = 0; t < TT; ++t) {
            u16* s1cur = s1b + (t & 1) * SPAN;

            // s1 parity throttle (owner): C(t) overwrites s1(t-2); readers done
            // iff fD >= t-1.
            if (own && t >= 2) wait_all(fD, (unsigned)(t - 1), lane);

            // ---- C: alpha1(t); s1(t) publish. h1(t-1) finished here (deferred
            //      D-reduce from planeD written in D(t-1)).
            f32x4 c[4];
            #pragma unroll
            for (int nt = 0; nt < 4; ++nt) c[nt] = pC1[nt];
            mm4(c, fh, wWax1, n0, lrow, wv, lkg);
            red_put(red, 0, c, wv, lane);
            __syncthreads();                               // (1)
            if (own) {
                if (t > 0) {
                    f32x4 dsum = red_get(red, 1, dOwn, wv, lane);
                    #pragma unroll
                    for (int r = 0; r < 4; ++r)
                        h1l[r] = tanhf(dsum[r] + ((const float*)&vbh1)[r]);
                }
                f32x4 cOwn = zf;
                #pragma unroll
                for (int nt = 0; nt < 4; ++nt) if (nt == wv) cOwn = c[nt];
                f32x4 csum = red_get(red, 0, cOwn, wv, lane);
                float sb[4];
                #pragma unroll
                for (int r = 0; r < 4; ++r) {
                    float al = 1.f / (1.f + __expf(-(csum[r] + ((const float*)&vba1)[r])));
                    sb[r] = al * h1l[r] + (1.f - al) * s1l[r];
                    s1l[r] = sb[r];
                }
                agent_store64((u64*)(s1cur + (size_t)(m0 + lrow) * HH + nb),
                              pack4(sb[0], sb[1], sb[2], sb[3]));
            }
            __syncthreads();                               // (2) drain stores
            flag_set(fC, wgl, (unsigned)(t + 1), tid);

            // exchange window: pD1 = Wih1 h0(t); prefetch fh(t+1) from ring.
            f32x4 pD1[4];
            #pragma unroll
            for (int nt = 0; nt < 4; ++nt) pD1[nt] = zf;
            mm4(pD1, fh, wWih1, n0, lrow, wv, lkg);
            if (t + 1 < TT) {
                wait2(fB, wv, (unsigned)(t + 2), lane);    // L0 far ahead
                load_frags(fh, h0r + (size_t)((t + 1) & (RING - 1)) * SPAN,
                           arow, wv, lkg);
            }

            // ---- D: wait s1(t); GEMMs; put partials (reduce deferred to C(t+1))
            wait2(fC, wv, (unsigned)(t + 1), lane);
            short8 fs1[4];
            load_frags(fs1, s1cur, arow, wv, lkg);
            mm4(pD1, fs1, wWhh1, n0, lrow, wv, lkg);
            #pragma unroll
            for (int nt = 0; nt < 4; ++nt) pC1[nt] = zf;
            mm4(pC1, fs1, wUas1, n0, lrow, wv, lkg);
            red_put(red, 1, pD1, wv, lane);
            #pragma unroll
            for (int nt = 0; nt < 4; ++nt) if (nt == wv) dOwn = pD1[nt];
            __syncthreads();                               // (3) fs1 consumed
            flag_set(fD, wgl, (unsigned)(t + 1), tid);
        }

        // final h1 (deferred reduce of D(TT-1))
        if (own) {
            f32x4 dsum = red_get(red, 1, dOwn, wv, lane);
            #pragma unroll
            for (int r = 0; r < 4; ++r)
                h1l[r] = tanhf(dsum[r] + ((const float*)&vbh1)[r]);

            const size_t o = (size_t)(m0 + lrow) * HH + nb;
            *(float4*)(out + HIDB + SPAN + o) = make_float4(h1l[0], h1l[1], h1l[2], h1l[3]);
            *(float4*)(out + SMOB + SPAN + o) = make_float4(s1l[0], s1l[1], s1l[2], s1l[3]);

            const float4 w4 = *(const float4*)(fcW + nb);
            float v = h1l[0] * w4.x + h1l[1] * w4.y + h1l[2] * w4.z + h1l[3] * w4.w;
            v += __shfl_xor(v, 16);
            v += __shfl_xor(v, 32);
            if (lane < 16) {
                if (ngg == 0 && wv == 0) v += fcb[0];
                atomicAdd(out + m0 + lane, v);
            }
        }
    }
}

extern "C" void kernel_launch(void* const* d_in, const int* in_sizes, int n_in,
                              void* d_out, int out_size, void* d_ws, size_t ws_size,
                              hipStream_t stream)
{
    const float* x    = (const float*)d_in[0];
    const float* Wax0 = (const float*)d_in[1];
    const float* Uas0 = (const float*)d_in[2];
    const float* ba0  = (const float*)d_in[3];
    const float* Wih0 = (const float*)d_in[4];
    const float* Whh0 = (const float*)d_in[5];
    const float* bh0  = (const float*)d_in[6];
    const float* Wax1 = (const float*)d_in[7];
    const float* Uas1 = (const float*)d_in[8];
    const float* ba1  = (const float*)d_in[9];
    const float* Wih1 = (const float*)d_in[10];
    const float* Whh1 = (const float*)d_in[11];
    const float* bh1  = (const float*)d_in[12];
    const float* fcW  = (const float*)d_in[13];
    const float* fcb  = (const float*)d_in[14];
    float* out = (float*)d_out;

    char* ws = (char*)d_ws;
    u16* s0b = (u16*)(ws + S0_OFF);
    u16* s1b = (u16*)(ws + S1_OFF);
    u16* h0r = (u16*)(ws + H0_OFF);
    unsigned* flags = (unsigned*)(ws + FL_OFF);
    u16* wbase = (u16*)(ws + W_OFF);
    u16* wUas0 = wbase + 0 * 1048576;
    u16* wWhh0 = wbase + 1 * 1048576;
    u16* wWax1 = wbase + 2 * 1048576;
    u16* wUas1 = wbase + 3 * 1048576;
    u16* wWih1 = wbase + 4 * 1048576;
    u16* wWhh1 = wbase + 5 * 1048576;
    u16* wWax0 = wbase + 6 * 1048576;
    u16* wWih0 = wbase + 6 * 1048576 + 262144;

    hipMemsetAsync(d_ws, 0, W_OFF, stream);
    hipMemsetAsync(d_out, 0, (size_t)out_size * sizeof(float), stream);

    conv_weights<<<dim3(1024), dim3(256), 0, stream>>>(
        Uas0, Whh0, Wax1, Uas1, Wih1, Whh1, Wax0, Wih0, wbase);

    alphat_mfma<<<dim3(256), dim3(NTHR), 0, stream>>>(
        x, wUas0, wWhh0, wWax1, wUas1, wWih1, wWhh1, wWax0, wWih0,
        ba0, bh0, ba1, bh1, fcW, fcb, out, s0b, s1b, h0r, flags);
}

// Round 16
// 11620.868 us; speedup vs baseline: 1.0155x; 1.0155x over previous
//
#include <hip/hip_runtime.h>

// AlphatRNN B=128,T=512,D=256,H=1024,L=2,O=1 — bf16 MFMA persistent kernel, R16.
// R16 = R14 skeleton (two pools, 10.3ms, PASSING) + REGISTER-RESIDENT serial-
// path weights: L0 holds Whh0+Uas0 slices in VGPRs (16+16 short8/lane), L1
// holds Uas1+Whh1. The recurrence GEMMs become pure-register MFMA -> no L2
// weight stream on the serial path, no per-step L2 queuing jitter (the
// suspected straggler source). L1's fC window now also prefetches fh(t+1) and
// precomputes cAx=Wax1*h0(t+1) (ring-fed, off-path), so C's serial part is
// add+sigmoid+publish. Sync/flags/reduce/throttles = R14 verbatim.

typedef unsigned short u16;
typedef unsigned long long u64;
typedef __attribute__((ext_vector_type(8))) short short8;
typedef __attribute__((ext_vector_type(4))) float f32x4;

#define NB   128
#define TT   512
#define DD   256
#define HH   1024
#define NTHR 512
#define SPAN (NB * HH)
#define RING 32
#define GS   16

// ---- ws layout (bytes) ----
#define S0_OFF  0u          // bf16 [2][128][1024] s0 parity
#define S1_OFF  524288u     // bf16 [2][128][1024] s1 parity
#define H0_OFF  1048576u    // bf16 [RING][128][1024] = 8 MB h0 ring
#define FL_OFF  9437184u    // fB/fC/fD: 3 x [8 mg][16 wgl] x 64 B = 24 KB
#define W_OFF   9486336u    // bf16 weights: 6x[1024][1024], then [1024][256]x2
#define NBIG    6291456u

__device__ __forceinline__ u16 f2bf(float f) {
    unsigned u = __builtin_bit_cast(unsigned, f);
    return (u16)((u + 0x7fffu + ((u >> 16) & 1u)) >> 16);
}
__device__ __forceinline__ u64 agent_load64(const u64* p) {
    return __hip_atomic_load(p, __ATOMIC_RELAXED, __HIP_MEMORY_SCOPE_AGENT);
}
__device__ __forceinline__ void agent_store64(u64* p, u64 v) {
    __hip_atomic_store(p, v, __ATOMIC_RELAXED, __HIP_MEMORY_SCOPE_AGENT);
}

// R14 flag primitives (verbatim): set = sync (drain) + tid0 release store;
// wait = lanes 0..15 poll + WG sync.
__device__ __forceinline__ void flag_set(unsigned* f, int wgl, unsigned val, int tid)
{
    __syncthreads();
    if (tid == 0)
        __hip_atomic_store(f + wgl * 16, val, __ATOMIC_RELEASE,
                           __HIP_MEMORY_SCOPE_AGENT);
}
__device__ __forceinline__ void flag_wait(unsigned* f, unsigned val, int tid)
{
    if (tid < GS)
        while (__hip_atomic_load(f + tid * 16, __ATOMIC_RELAXED,
                                 __HIP_MEMORY_SCOPE_AGENT) < val)
            __builtin_amdgcn_s_sleep(1);
    __syncthreads();
}

// state frags, one K-EIGHTH (128 k): lane(lrow,lkg) reads row m0+lrow,
// k = wv*128 + s*32 + lkg*8, s=0..3. sc1 loads from a published span.
__device__ __forceinline__ void load_frags(short8* fr, const u16* base,
                                           int row, int wv, int lkg)
{
    const u16* sp = base + ((size_t)row << 10) + wv * 128 + lkg * 8;
    #pragma unroll
    for (int s = 0; s < 4; ++s) {
        union { short8 v; u64 q[2]; } u_;
        u_.q[0] = agent_load64((const u64*)(sp + s * 32));
        u_.q[1] = agent_load64((const u64*)(sp + s * 32 + 4));
        fr[s] = u_.v;
    }
}

// load a 16-short8 register weight slice (4 nt x 4 s), fully unrolled.
__device__ __forceinline__ void load_wreg(short8* w, const u16* W,
                                          int n0, int lrow, int wv, int lkg)
{
    #pragma unroll
    for (int nt = 0; nt < 4; ++nt)
        #pragma unroll
        for (int s = 0; s < 4; ++s)
            w[nt * 4 + s] = *(const short8*)(W
                + ((size_t)(n0 + nt * 16 + lrow) << 10) + wv * 128 + s * 32 + lkg * 8);
}

// a[nt] += Wreg (x) S(frags): pure-register MFMA (no memory on serial path).
__device__ __forceinline__ void mm4r(f32x4* a, const short8* fr, const short8* w)
{
    #pragma unroll
    for (int nt = 0; nt < 4; ++nt)
        #pragma unroll
        for (int s = 0; s < 4; ++s)
            a[nt] = __builtin_amdgcn_mfma_f32_16x16x32_bf16(
                w[nt * 4 + s], fr[s], a[nt], 0, 0, 0);
}

// streamed variant (off-path GEMMs: Wax1/Wih1 on h0).
__device__ __forceinline__ void mm4(f32x4* a, const short8* fr, const u16* W,
                                    int n0, int lrow, int wv, int lkg)
{
    #pragma unroll
    for (int nt = 0; nt < 4; ++nt) {
        const u16* wp = W + ((size_t)(n0 + nt * 16 + lrow) << 10) + wv * 128 + lkg * 8;
        #pragma unroll
        for (int s = 0; s < 4; ++s)
            a[nt] = __builtin_amdgcn_mfma_f32_16x16x32_bf16(
                *(const short8*)(wp + s * 32), fr[s], a[nt], 0, 0, 0);
    }
}

// a[nt] += Wx[n0+nt*16+lrow, K-eighth of 256] (x) x_row(fp32->bf16), streamed.
__device__ __forceinline__ void mmx4(f32x4* a, const float* xrow, const u16* W,
                                     int n0, int lrow, int wv, int lkg)
{
    const float* p = xrow + wv * 32 + lkg * 8;
    float4 A = *(const float4*)p;
    float4 B = *(const float4*)(p + 4);
    short8 v;
    v[0]=(short)f2bf(A.x); v[1]=(short)f2bf(A.y); v[2]=(short)f2bf(A.z); v[3]=(short)f2bf(A.w);
    v[4]=(short)f2bf(B.x); v[5]=(short)f2bf(B.y); v[6]=(short)f2bf(B.z); v[7]=(short)f2bf(B.w);
    #pragma unroll
    for (int nt = 0; nt < 4; ++nt) {
        const u16* wp = W + ((size_t)(n0 + nt * 16 + lrow) << 8) + wv * 32 + lkg * 8;
        a[nt] = __builtin_amdgcn_mfma_f32_16x16x32_bf16(
            *(const short8*)wp, v, a[nt], 0, 0, 0);
    }
}

// 32KB reduce plane [comp][nt][wave][lane] (R14 verbatim, conflict-free).
__device__ __forceinline__ void red_put(float (*red)[4][8][64], const f32x4* a,
                                        int wv, int lane)
{
    #pragma unroll
    for (int nt = 0; nt < 4; ++nt)
        #pragma unroll
        for (int c = 0; c < 4; ++c) red[c][nt][wv][lane] = a[nt][c];
}
__device__ __forceinline__ f32x4 red_get(float (*red)[4][8][64], int nt, int lane)
{
    f32x4 v = {0.f, 0.f, 0.f, 0.f};
    #pragma unroll
    for (int j = 0; j < 8; ++j)
        #pragma unroll
        for (int c = 0; c < 4; ++c) v[c] += red[c][nt][j][lane];
    return v;
}

__device__ __forceinline__ u64 pack4(float a, float b, float c, float d)
{
    return (u64)f2bf(a) | ((u64)f2bf(b) << 16) | ((u64)f2bf(c) << 32)
         | ((u64)f2bf(d) << 48);
}

__global__ void conv_weights(const float* Uas0, const float* Whh0, const float* Wax1,
                             const float* Uas1, const float* Wih1, const float* Whh1,
                             const float* Wax0, const float* Wih0, u16* dst)
{
    for (size_t i = (size_t)blockIdx.x * blockDim.x + threadIdx.x; i < 6815744u;
         i += (size_t)gridDim.x * blockDim.x) {
        const float* src; size_t off;
        if (i < NBIG) {
            int seg = (int)(i >> 20); off = i & 1048575u;
            src = seg == 0 ? Uas0 : seg == 1 ? Whh0 : seg == 2 ? Wax1
                : seg == 3 ? Uas1 : seg == 4 ? Wih1 : Whh1;
        } else {
            size_t j = i - NBIG; off = j & 262143u;
            src = (j >> 18) ? Wih0 : Wax0;
        }
        dst[i] = f2bf(src[off]);
    }
}

extern "C" __global__ void __launch_bounds__(NTHR, 1)
alphat_mfma(const float* __restrict__ x,
            const u16* __restrict__ wUas0, const u16* __restrict__ wWhh0,
            const u16* __restrict__ wWax1, const u16* __restrict__ wUas1,
            const u16* __restrict__ wWih1, const u16* __restrict__ wWhh1,
            const u16* __restrict__ wWax0, const u16* __restrict__ wWih0,
            const float* __restrict__ ba0, const float* __restrict__ bh0,
            const float* __restrict__ ba1, const float* __restrict__ bh1,
            const float* __restrict__ fcW, const float* __restrict__ fcb,
            float* __restrict__ out,
            u16* s0b, u16* s1b, u16* h0r, unsigned* flags)
{
    __shared__ float red[4][4][8][64];   // 32 KB, one plane set (serial reuse)

    const int tid  = threadIdx.x;
    const int wv   = tid >> 6;           // K-eighth; waves 0-3 own n-tiles 0-3
    const int lane = tid & 63;
    const int lrow = lane & 15;
    const int lkg  = lane >> 4;

    const bool isL0 = (blockIdx.x < 128);
    const int wg  = isL0 ? blockIdx.x : (blockIdx.x - 128);
    const int ngg = (wg & 7) * 2 + ((wg >> 3) & 1);
    const int mg  = wg >> 4;
    const int wgl = wg & 15;
    const int m0  = mg * 16;
    const int n0  = ngg * 64;

    unsigned* fB = flags + (size_t)mg * 256;
    unsigned* fC = flags + 2048 + (size_t)mg * 256;
    unsigned* fD = flags + 4096 + (size_t)mg * 256;

    const int arow = m0 + lrow;
    const bool own = (wv < 4);
    const int nb   = n0 + (wv & 3) * 16 + lkg * 4;

    const f32x4 zf = {0.f, 0.f, 0.f, 0.f};
    const size_t HIDB = NB, SMOB = NB + 2 * (size_t)SPAN;

    if (isL0) {
        // ============ layer-0 pool: B chain, reg-resident Whh0/Uas0 ==========
        short8 wh[16], wu[16];
        load_wreg(wh, wWhh0, n0, lrow, wv, lkg);
        load_wreg(wu, wUas0, n0, lrow, wv, lkg);

        float4 vba0 = {0,0,0,0}, vbh0 = {0,0,0,0};
        if (own) { vba0 = *(const float4*)(ba0 + nb); vbh0 = *(const float4*)(bh0 + nb); }
        float h0l[4] = {0,0,0,0}, s0l[4] = {0,0,0,0};

        short8 frags[4];
        #pragma unroll
        for (int s = 0; s < 4; ++s)
            #pragma unroll
            for (int i = 0; i < 8; ++i) frags[s][i] = 0;
        const float* xbase = x + (size_t)arow * (TT * DD);
        f32x4 pBx[4], pAx[4];
        #pragma unroll
        for (int nt = 0; nt < 4; ++nt) { pBx[nt] = zf; pAx[nt] = zf; }
        mmx4(pBx, xbase + 0 * DD, wWih0, n0, lrow, wv, lkg);
        mmx4(pAx, xbase + 1 * DD, wWax0, n0, lrow, wv, lkg);

        for (int t = 0; t < TT; ++t) {
            u16* h0cur = h0r + (size_t)(t & (RING - 1)) * SPAN;
            u16* s0nxt = s0b + ((t + 1) & 1) * SPAN;

            if (t >= RING) flag_wait(fC, (unsigned)(t - RING + 1), tid);

            f32x4 acc[4], pA[4];
            #pragma unroll
            for (int nt = 0; nt < 4; ++nt) { acc[nt] = pBx[nt]; pA[nt] = pAx[nt]; }
            mm4r(acc, frags, wh);            // pure-register serial GEMMs
            mm4r(pA,  frags, wu);

            red_put(red, acc, wv, lane);
            __syncthreads();
            f32x4 hsum = zf;
            if (own) hsum = red_get(red, wv, lane);
            __syncthreads();
            red_put(red, pA, wv, lane);
            __syncthreads();
            if (own) {
                f32x4 asum = red_get(red, wv, lane);
                float hb[4];
                #pragma unroll
                for (int r = 0; r < 4; ++r) {
                    hb[r] = tanhf(hsum[r] + ((const float*)&vbh0)[r]);
                    h0l[r] = hb[r];
                }
                agent_store64((u64*)(h0cur + (size_t)(m0 + lrow) * HH + nb),
                              pack4(hb[0], hb[1], hb[2], hb[3]));
                if (t + 1 < TT) {
                    float sb[4];
                    #pragma unroll
                    for (int r = 0; r < 4; ++r) {
                        float al = 1.f / (1.f + __expf(-(asum[r] + ((const float*)&vba0)[r])));
                        sb[r] = al * hb[r] + (1.f - al) * s0l[r];
                        s0l[r] = sb[r];
                    }
                    agent_store64((u64*)(s0nxt + (size_t)(m0 + lrow) * HH + nb),
                                  pack4(sb[0], sb[1], sb[2], sb[3]));
                }
            }
            flag_set(fB, wgl, (unsigned)(t + 1), tid);

            if (t + 1 < TT) {
                // exchange window: next x partials (streamed, off-path)
                #pragma unroll
                for (int nt = 0; nt < 4; ++nt) pBx[nt] = zf;
                mmx4(pBx, xbase + (size_t)(t + 1) * DD, wWih0, n0, lrow, wv, lkg);
                if (t + 2 < TT) {
                    #pragma unroll
                    for (int nt = 0; nt < 4; ++nt) pAx[nt] = zf;
                    mmx4(pAx, xbase + (size_t)(t + 2) * DD, wWax0, n0, lrow, wv, lkg);
                }
                flag_wait(fB, (unsigned)(t + 1), tid);
                load_frags(frags, s0nxt, arow, wv, lkg);
            }
        }
        if (own) {
            const size_t o = (size_t)(m0 + lrow) * HH + nb;
            *(float4*)(out + HIDB + o) = make_float4(h0l[0], h0l[1], h0l[2], h0l[3]);
            *(float4*)(out + SMOB + o) = make_float4(s0l[0], s0l[1], s0l[2], s0l[3]);
        }
    } else {
        // ============ layer-1 pool: C+D, reg-resident Uas1/Whh1 ==============
        short8 wu1[16], wh1[16];
        load_wreg(wu1, wUas1, n0, lrow, wv, lkg);
        load_wreg(wh1, wWhh1, n0, lrow, wv, lkg);

        float4 vba1 = {0,0,0,0}, vbh1 = {0,0,0,0};
        if (own) { vba1 = *(const float4*)(ba1 + nb); vbh1 = *(const float4*)(bh1 + nb); }
        float h1l[4] = {0,0,0,0}, s1l[4] = {0,0,0,0};
        f32x4 pC1[4], cAx[4];
        #pragma unroll
        for (int nt = 0; nt < 4; ++nt) pC1[nt] = zf;   // Uas1 s1(-1) = 0

        // prologue: fh(0) + cAx(0) = Wax1 h0(0) (streamed, ring-fed)
        short8 fh[4];
        flag_wait(fB, 1u, tid);
        load_frags(fh, h0r, arow, wv, lkg);
        #pragma unroll
        for (int nt = 0; nt < 4; ++nt) cAx[nt] = zf;
        mm4(cAx, fh, wWax1, n0, lrow, wv, lkg);

        for (int t = 0; t < TT; ++t) {
            u16* s1cur = s1b + (t & 1) * SPAN;

            if (t >= 2) flag_wait(fD, (unsigned)(t - 1), tid);

            // ---- C: alpha1(t) = sig(pC1 + cAx + ba1); publish s1(t) ----
            f32x4 c[4];
            #pragma unroll
            for (int nt = 0; nt < 4; ++nt) c[nt] = pC1[nt] + cAx[nt];
            red_put(red, c, wv, lane);
            __syncthreads();
            if (own) {
                f32x4 csum = red_get(red, wv, lane);
                float sb[4];
                #pragma unroll
                for (int r = 0; r < 4; ++r) {
                    float al = 1.f / (1.f + __expf(-(csum[r] + ((const float*)&vba1)[r])));
                    sb[r] = al * h1l[r] + (1.f - al) * s1l[r];
                    s1l[r] = sb[r];
                }
                agent_store64((u64*)(s1cur + (size_t)(m0 + lrow) * HH + nb),
                              pack4(sb[0], sb[1], sb[2], sb[3]));
            }
            flag_set(fC, wgl, (unsigned)(t + 1), tid);

            // exchange window (off-path): pD1 = Wih1 h0(t); prefetch fh(t+1);
            // cAx(t+1) = Wax1 h0(t+1). All streamed; ring is steps ahead.
            f32x4 pD1[4];
            #pragma unroll
            for (int nt = 0; nt < 4; ++nt) pD1[nt] = zf;
            mm4(pD1, fh, wWih1, n0, lrow, wv, lkg);
            if (t + 1 < TT) {
                flag_wait(fB, (unsigned)(t + 2), tid);
                load_frags(fh, h0r + (size_t)((t + 1) & (RING - 1)) * SPAN,
                           arow, wv, lkg);
                #pragma unroll
                for (int nt = 0; nt < 4; ++nt) cAx[nt] = zf;
                mm4(cAx, fh, wWax1, n0, lrow, wv, lkg);
            }

            // ---- D: wait s1(t); reg GEMMs; h1(t); pC1 for C(t+1) ----
            flag_wait(fC, (unsigned)(t + 1), tid);
            short8 fs1[4];
            load_frags(fs1, s1cur, arow, wv, lkg);
            mm4r(pD1, fs1, wh1);
            #pragma unroll
            for (int nt = 0; nt < 4; ++nt) pC1[nt] = zf;
            mm4r(pC1, fs1, wu1);
            red_put(red, pD1, wv, lane);
            __syncthreads();
            if (own) {
                f32x4 dsum = red_get(red, wv, lane);
                #pragma unroll
                for (int r = 0; r < 4; ++r)
                    h1l[r] = tanhf(dsum[r] + ((const float*)&vbh1)[r]);
            }
            flag_set(fD, wgl, (unsigned)(t + 1), tid);
        }
        if (own) {
            const size_t o = (size_t)(m0 + lrow) * HH + nb;
            *(float4*)(out + HIDB + SPAN + o) = make_float4(h1l[0], h1l[1], h1l[2], h1l[3]);
            *(float4*)(out + SMOB + SPAN + o) = make_float4(s1l[0], s1l[1], s1l[2], s1l[3]);

            const float4 w4 = *(const float4*)(fcW + nb);
            float v = h1l[0] * w4.x + h1l[1] * w4.y + h1l[2] * w4.z + h1l[3] * w4.w;
            v += __shfl_xor(v, 16);
            v += __shfl_xor(v, 32);
            if (lane < 16) {
                if (ngg == 0 && wv == 0) v += fcb[0];
                atomicAdd(out + m0 + lane, v);
            }
        }
    }
}

extern "C" void kernel_launch(void* const* d_in, const int* in_sizes, int n_in,
                              void* d_out, int out_size, void* d_ws, size_t ws_size,
                              hipStream_t stream)
{
    const float* x    = (const float*)d_in[0];
    const float* Wax0 = (const float*)d_in[1];
    const float* Uas0 = (const float*)d_in[2];
    const float* ba0  = (const float*)d_in[3];
    const float* Wih0 = (const float*)d_in[4];
    const float* Whh0 = (const float*)d_in[5];
    const float* bh0  = (const float*)d_in[6];
    const float* Wax1 = (const float*)d_in[7];
    const float* Uas1 = (const float*)d_in[8];
    const float* ba1  = (const float*)d_in[9];
    const float* Wih1 = (const float*)d_in[10];
    const float* Whh1 = (const float*)d_in[11];
    const float* bh1  = (const float*)d_in[12];
    const float* fcW  = (const float*)d_in[13];
    const float* fcb  = (const float*)d_in[14];
    float* out = (float*)d_out;

    char* ws = (char*)d_ws;
    u16* s0b = (u16*)(ws + S0_OFF);
    u16* s1b = (u16*)(ws + S1_OFF);
    u16* h0r = (u16*)(ws + H0_OFF);
    unsigned* flags = (unsigned*)(ws + FL_OFF);
    u16* wbase = (u16*)(ws + W_OFF);
    u16* wUas0 = wbase + 0 * 1048576;
    u16* wWhh0 = wbase + 1 * 1048576;
    u16* wWax1 = wbase + 2 * 1048576;
    u16* wUas1 = wbase + 3 * 1048576;
    u16* wWih1 = wbase + 4 * 1048576;
    u16* wWhh1 = wbase + 5 * 1048576;
    u16* wWax0 = wbase + 6 * 1048576;
    u16* wWih0 = wbase + 6 * 1048576 + 262144;

    hipMemsetAsync(d_ws, 0, W_OFF, stream);
    hipMemsetAsync(d_out, 0, (size_t)out_size * sizeof(float), stream);

    conv_weights<<<dim3(1024), dim3(256), 0, stream>>>(
        Uas0, Whh0, Wax1, Uas1, Wih1, Whh1, Wax0, Wih0, wbase);

    alphat_mfma<<<dim3(256), dim3(NTHR), 0, stream>>>(
        x, wUas0, wWhh0, wWax1, wUas1, wWih1, wWhh1, wWax0, wWih0,
        ba0, bh0, ba1, bh1, fcW, fcb, out, s0b, s1b, h0r, flags);
}

// Round 17
// 11576.821 us; speedup vs baseline: 1.0194x; 1.0038x over previous
//
#include <hip/hip_runtime.h>

// AlphatRNN B=128,T=512,D=256,H=1024,L=2,O=1 — bf16 MFMA persistent kernel, R17.
// R17 = R14 skeleton (two pools, 10.3ms champion) + L1 SERIAL-PATH-ONLY moves
// (isolating R16's confound — no register-weight gamble):
//  (a) cAx = Wax1*h0(t) hoisted into the previous step's exchange window,
//  (b) pC1 = Uas1*s1(t) moved AFTER the fD flag (needed only at C(t+1)),
//  (c) fD set right after red_put+sync (fs1 loads drained; reduce/tanh after).
// L1 serial/step: wait fC -> load fs1 -> Whh1 GEMM -> red_put -> fD.
// L0 pool and all sync primitives = R14 verbatim.

typedef unsigned short u16;
typedef unsigned long long u64;
typedef __attribute__((ext_vector_type(8))) short short8;
typedef __attribute__((ext_vector_type(4))) float f32x4;

#define NB   128
#define TT   512
#define DD   256
#define HH   1024
#define NTHR 512
#define SPAN (NB * HH)
#define RING 32
#define GS   16

// ---- ws layout (bytes) ----
#define S0_OFF  0u          // bf16 [2][128][1024] s0 parity
#define S1_OFF  524288u     // bf16 [2][128][1024] s1 parity
#define H0_OFF  1048576u    // bf16 [RING][128][1024] = 8 MB h0 ring
#define FL_OFF  9437184u    // fB/fC/fD: 3 x [8 mg][16 wgl] x 64 B = 24 KB
#define W_OFF   9486336u    // bf16 weights: 6x[1024][1024], then [1024][256]x2
#define NBIG    6291456u

__device__ __forceinline__ u16 f2bf(float f) {
    unsigned u = __builtin_bit_cast(unsigned, f);
    return (u16)((u + 0x7fffu + ((u >> 16) & 1u)) >> 16);
}
__device__ __forceinline__ u64 agent_load64(const u64* p) {
    return __hip_atomic_load(p, __ATOMIC_RELAXED, __HIP_MEMORY_SCOPE_AGENT);
}
__device__ __forceinline__ void agent_store64(u64* p, u64 v) {
    __hip_atomic_store(p, v, __ATOMIC_RELAXED, __HIP_MEMORY_SCOPE_AGENT);
}

// R14 flag primitives (verbatim): set = sync (drain) + tid0 release store;
// wait = lanes 0..15 poll + WG sync.
__device__ __forceinline__ void flag_set(unsigned* f, int wgl, unsigned val, int tid)
{
    __syncthreads();
    if (tid == 0)
        __hip_atomic_store(f + wgl * 16, val, __ATOMIC_RELEASE,
                           __HIP_MEMORY_SCOPE_AGENT);
}
__device__ __forceinline__ void flag_wait(unsigned* f, unsigned val, int tid)
{
    if (tid < GS)
        while (__hip_atomic_load(f + tid * 16, __ATOMIC_RELAXED,
                                 __HIP_MEMORY_SCOPE_AGENT) < val)
            __builtin_amdgcn_s_sleep(1);
    __syncthreads();
}

// state frags, one K-EIGHTH (128 k): lane(lrow,lkg) reads row m0+lrow,
// k = wv*128 + s*32 + lkg*8, s=0..3. sc1 loads from a published span.
__device__ __forceinline__ void load_frags(short8* fr, const u16* base,
                                           int row, int wv, int lkg)
{
    const u16* sp = base + ((size_t)row << 10) + wv * 128 + lkg * 8;
    #pragma unroll
    for (int s = 0; s < 4; ++s) {
        union { short8 v; u64 q[2]; } u_;
        u_.q[0] = agent_load64((const u64*)(sp + s * 32));
        u_.q[1] = agent_load64((const u64*)(sp + s * 32 + 4));
        fr[s] = u_.v;
    }
}

// a[nt] += W[n0+nt*16+lrow, K-eighth] (x) S(frags), swapped operands
// (D rows = W rows = H-cols, D cols = batch). 16 mfma per call. Streamed.
__device__ __forceinline__ void mm4(f32x4* a, const short8* fr, const u16* W,
                                    int n0, int lrow, int wv, int lkg)
{
    #pragma unroll
    for (int nt = 0; nt < 4; ++nt) {
        const u16* wp = W + ((size_t)(n0 + nt * 16 + lrow) << 10) + wv * 128 + lkg * 8;
        #pragma unroll
        for (int s = 0; s < 4; ++s)
            a[nt] = __builtin_amdgcn_mfma_f32_16x16x32_bf16(
                *(const short8*)(wp + s * 32), fr[s], a[nt], 0, 0, 0);
    }
}

// a[nt] += Wx[n0+nt*16+lrow, K-eighth of 256] (x) x_row(fp32->bf16), streamed.
__device__ __forceinline__ void mmx4(f32x4* a, const float* xrow, const u16* W,
                                     int n0, int lrow, int wv, int lkg)
{
    const float* p = xrow + wv * 32 + lkg * 8;
    float4 A = *(const float4*)p;
    float4 B = *(const float4*)(p + 4);
    short8 v;
    v[0]=(short)f2bf(A.x); v[1]=(short)f2bf(A.y); v[2]=(short)f2bf(A.z); v[3]=(short)f2bf(A.w);
    v[4]=(short)f2bf(B.x); v[5]=(short)f2bf(B.y); v[6]=(short)f2bf(B.z); v[7]=(short)f2bf(B.w);
    #pragma unroll
    for (int nt = 0; nt < 4; ++nt) {
        const u16* wp = W + ((size_t)(n0 + nt * 16 + lrow) << 8) + wv * 32 + lkg * 8;
        a[nt] = __builtin_amdgcn_mfma_f32_16x16x32_bf16(
            *(const short8*)wp, v, a[nt], 0, 0, 0);
    }
}

// 32KB reduce plane [comp][nt][wave][lane] (R14 verbatim, conflict-free).
__device__ __forceinline__ void red_put(float (*red)[4][8][64], const f32x4* a,
                                        int wv, int lane)
{
    #pragma unroll
    for (int nt = 0; nt < 4; ++nt)
        #pragma unroll
        for (int c = 0; c < 4; ++c) red[c][nt][wv][lane] = a[nt][c];
}
__device__ __forceinline__ f32x4 red_get(float (*red)[4][8][64], int nt, int lane)
{
    f32x4 v = {0.f, 0.f, 0.f, 0.f};
    #pragma unroll
    for (int j = 0; j < 8; ++j)
        #pragma unroll
        for (int c = 0; c < 4; ++c) v[c] += red[c][nt][j][lane];
    return v;
}

__device__ __forceinline__ u64 pack4(float a, float b, float c, float d)
{
    return (u64)f2bf(a) | ((u64)f2bf(b) << 16) | ((u64)f2bf(c) << 32)
         | ((u64)f2bf(d) << 48);
}

__global__ void conv_weights(const float* Uas0, const float* Whh0, const float* Wax1,
                             const float* Uas1, const float* Wih1, const float* Whh1,
                             const float* Wax0, const float* Wih0, u16* dst)
{
    for (size_t i = (size_t)blockIdx.x * blockDim.x + threadIdx.x; i < 6815744u;
         i += (size_t)gridDim.x * blockDim.x) {
        const float* src; size_t off;
        if (i < NBIG) {
            int seg = (int)(i >> 20); off = i & 1048575u;
            src = seg == 0 ? Uas0 : seg == 1 ? Whh0 : seg == 2 ? Wax1
                : seg == 3 ? Uas1 : seg == 4 ? Wih1 : Whh1;
        } else {
            size_t j = i - NBIG; off = j & 262143u;
            src = (j >> 18) ? Wih0 : Wax0;
        }
        dst[i] = f2bf(src[off]);
    }
}

extern "C" __global__ void __launch_bounds__(NTHR, 1)
alphat_mfma(const float* __restrict__ x,
            const u16* __restrict__ wUas0, const u16* __restrict__ wWhh0,
            const u16* __restrict__ wWax1, const u16* __restrict__ wUas1,
            const u16* __restrict__ wWih1, const u16* __restrict__ wWhh1,
            const u16* __restrict__ wWax0, const u16* __restrict__ wWih0,
            const float* __restrict__ ba0, const float* __restrict__ bh0,
            const float* __restrict__ ba1, const float* __restrict__ bh1,
            const float* __restrict__ fcW, const float* __restrict__ fcb,
            float* __restrict__ out,
            u16* s0b, u16* s1b, u16* h0r, unsigned* flags)
{
    __shared__ float red[4][4][8][64];   // 32 KB, one plane set (serial reuse)

    const int tid  = threadIdx.x;
    const int wv   = tid >> 6;           // K-eighth; waves 0-3 own n-tiles 0-3
    const int lane = tid & 63;
    const int lrow = lane & 15;
    const int lkg  = lane >> 4;

    const bool isL0 = (blockIdx.x < 128);
    const int wg  = isL0 ? blockIdx.x : (blockIdx.x - 128);
    const int ngg = (wg & 7) * 2 + ((wg >> 3) & 1);
    const int mg  = wg >> 4;
    const int wgl = wg & 15;
    const int m0  = mg * 16;
    const int n0  = ngg * 64;

    unsigned* fB = flags + (size_t)mg * 256;
    unsigned* fC = flags + 2048 + (size_t)mg * 256;
    unsigned* fD = flags + 4096 + (size_t)mg * 256;

    const int arow = m0 + lrow;
    const bool own = (wv < 4);
    const int nb   = n0 + (wv & 3) * 16 + lkg * 4;

    const f32x4 zf = {0.f, 0.f, 0.f, 0.f};
    const size_t HIDB = NB, SMOB = NB + 2 * (size_t)SPAN;

    if (isL0) {
        // ============ layer-0 pool: B chain (R14 verbatim) ===================
        float4 vba0 = {0,0,0,0}, vbh0 = {0,0,0,0};
        if (own) { vba0 = *(const float4*)(ba0 + nb); vbh0 = *(const float4*)(bh0 + nb); }
        float h0l[4] = {0,0,0,0}, s0l[4] = {0,0,0,0};

        short8 frags[4];
        #pragma unroll
        for (int s = 0; s < 4; ++s)
            #pragma unroll
            for (int i = 0; i < 8; ++i) frags[s][i] = 0;
        const float* xbase = x + (size_t)arow * (TT * DD);
        f32x4 pBx[4], pAx[4];
        #pragma unroll
        for (int nt = 0; nt < 4; ++nt) { pBx[nt] = zf; pAx[nt] = zf; }
        mmx4(pBx, xbase + 0 * DD, wWih0, n0, lrow, wv, lkg);
        mmx4(pAx, xbase + 1 * DD, wWax0, n0, lrow, wv, lkg);

        for (int t = 0; t < TT; ++t) {
            u16* h0cur = h0r + (size_t)(t & (RING - 1)) * SPAN;
            u16* s0nxt = s0b + ((t + 1) & 1) * SPAN;

            if (t >= RING) flag_wait(fC, (unsigned)(t - RING + 1), tid);

            f32x4 acc[4], pA[4];
            #pragma unroll
            for (int nt = 0; nt < 4; ++nt) { acc[nt] = pBx[nt]; pA[nt] = pAx[nt]; }
            mm4(acc, frags, wWhh0, n0, lrow, wv, lkg);
            mm4(pA,  frags, wUas0, n0, lrow, wv, lkg);

            red_put(red, acc, wv, lane);
            __syncthreads();
            f32x4 hsum = zf;
            if (own) hsum = red_get(red, wv, lane);
            __syncthreads();
            red_put(red, pA, wv, lane);
            __syncthreads();
            if (own) {
                f32x4 asum = red_get(red, wv, lane);
                float hb[4];
                #pragma unroll
                for (int r = 0; r < 4; ++r) {
                    hb[r] = tanhf(hsum[r] + ((const float*)&vbh0)[r]);
                    h0l[r] = hb[r];
                }
                agent_store64((u64*)(h0cur + (size_t)(m0 + lrow) * HH + nb),
                              pack4(hb[0], hb[1], hb[2], hb[3]));
                if (t + 1 < TT) {
                    float sb[4];
                    #pragma unroll
                    for (int r = 0; r < 4; ++r) {
                        float al = 1.f / (1.f + __expf(-(asum[r] + ((const float*)&vba0)[r])));
                        sb[r] = al * hb[r] + (1.f - al) * s0l[r];
                        s0l[r] = sb[r];
                    }
                    agent_store64((u64*)(s0nxt + (size_t)(m0 + lrow) * HH + nb),
                                  pack4(sb[0], sb[1], sb[2], sb[3]));
                }
            }
            flag_set(fB, wgl, (unsigned)(t + 1), tid);

            if (t + 1 < TT) {
                #pragma unroll
                for (int nt = 0; nt < 4; ++nt) pBx[nt] = zf;
                mmx4(pBx, xbase + (size_t)(t + 1) * DD, wWih0, n0, lrow, wv, lkg);
                if (t + 2 < TT) {
                    #pragma unroll
                    for (int nt = 0; nt < 4; ++nt) pAx[nt] = zf;
                    mmx4(pAx, xbase + (size_t)(t + 2) * DD, wWax0, n0, lrow, wv, lkg);
                }
                flag_wait(fB, (unsigned)(t + 1), tid);
                load_frags(frags, s0nxt, arow, wv, lkg);
            }
        }
        if (own) {
            const size_t o = (size_t)(m0 + lrow) * HH + nb;
            *(float4*)(out + HIDB + o) = make_float4(h0l[0], h0l[1], h0l[2], h0l[3]);
            *(float4*)(out + SMOB + o) = make_float4(s0l[0], s0l[1], s0l[2], s0l[3]);
        }
    } else {
        // ============ layer-1 pool: C+D with slimmed serial path =============
        float4 vba1 = {0,0,0,0}, vbh1 = {0,0,0,0};
        if (own) { vba1 = *(const float4*)(ba1 + nb); vbh1 = *(const float4*)(bh1 + nb); }
        float h1l[4] = {0,0,0,0}, s1l[4] = {0,0,0,0};
        f32x4 pC1[4], cAx[4];
        #pragma unroll
        for (int nt = 0; nt < 4; ++nt) pC1[nt] = zf;   // Uas1 s1(-1) = 0

        // prologue: fh(0); cAx(0) = Wax1 h0(0) (hoist (a), ring-fed)
        short8 fh[4];
        flag_wait(fB, 1u, tid);
        load_frags(fh, h0r, arow, wv, lkg);
        #pragma unroll
        for (int nt = 0; nt < 4; ++nt) cAx[nt] = zf;
        mm4(cAx, fh, wWax1, n0, lrow, wv, lkg);

        for (int t = 0; t < TT; ++t) {
            u16* s1cur = s1b + (t & 1) * SPAN;

            // s1 parity throttle + red-plane WAR vs D(t-1)'s red_get
            if (t >= 2) flag_wait(fD, (unsigned)(t - 1), tid);
            else        __syncthreads();   // red WAR for t<2 (no fD wait)

            // ---- C: alpha1(t) = sig(pC1 + cAx + ba1); publish s1(t) ----
            f32x4 c[4];
            #pragma unroll
            for (int nt = 0; nt < 4; ++nt) c[nt] = pC1[nt] + cAx[nt];
            red_put(red, c, wv, lane);
            __syncthreads();
            if (own) {
                f32x4 csum = red_get(red, wv, lane);
                float sb[4];
                #pragma unroll
                for (int r = 0; r < 4; ++r) {
                    float al = 1.f / (1.f + __expf(-(csum[r] + ((const float*)&vba1)[r])));
                    sb[r] = al * h1l[r] + (1.f - al) * s1l[r];
                    s1l[r] = sb[r];
                }
                agent_store64((u64*)(s1cur + (size_t)(m0 + lrow) * HH + nb),
                              pack4(sb[0], sb[1], sb[2], sb[3]));
            }
            flag_set(fC, wgl, (unsigned)(t + 1), tid);

            // exchange window (off-path): pD1 = Wih1 h0(t); prefetch fh(t+1);
            // cAx(t+1) = Wax1 h0(t+1) (hoist (a); ring is steps ahead).
            f32x4 pD1[4];
            #pragma unroll
            for (int nt = 0; nt < 4; ++nt) pD1[nt] = zf;
            mm4(pD1, fh, wWih1, n0, lrow, wv, lkg);
            if (t + 1 < TT) {
                flag_wait(fB, (unsigned)(t + 2), tid);
                load_frags(fh, h0r + (size_t)((t + 1) & (RING - 1)) * SPAN,
                           arow, wv, lkg);
                #pragma unroll
                for (int nt = 0; nt < 4; ++nt) cAx[nt] = zf;
                mm4(cAx, fh, wWax1, n0, lrow, wv, lkg);
            }

            // ---- D (serial): wait s1(t); load; Whh1 GEMM; red_put; fD ----
            flag_wait(fC, (unsigned)(t + 1), tid);
            short8 fs1[4];
            load_frags(fs1, s1cur, arow, wv, lkg);
            mm4(pD1, fs1, wWhh1, n0, lrow, wv, lkg);
            red_put(red, pD1, wv, lane);
            flag_set(fD, wgl, (unsigned)(t + 1), tid);   // (c) loads+LDS drained
            if (own) {
                f32x4 dsum = red_get(red, wv, lane);
                #pragma unroll
                for (int r = 0; r < 4; ++r)
                    h1l[r] = tanhf(dsum[r] + ((const float*)&vbh1)[r]);
            }
            // (b) off-path: pC1 for C(t+1) from register-held fs1
            #pragma unroll
            for (int nt = 0; nt < 4; ++nt) pC1[nt] = zf;
            mm4(pC1, fs1, wUas1, n0, lrow, wv, lkg);
        }
        if (own) {
            const size_t o = (size_t)(m0 + lrow) * HH + nb;
            *(float4*)(out + HIDB + SPAN + o) = make_float4(h1l[0], h1l[1], h1l[2], h1l[3]);
            *(float4*)(out + SMOB + SPAN + o) = make_float4(s1l[0], s1l[1], s1l[2], s1l[3]);

            const float4 w4 = *(const float4*)(fcW + nb);
            float v = h1l[0] * w4.x + h1l[1] * w4.y + h1l[2] * w4.z + h1l[3] * w4.w;
            v += __shfl_xor(v, 16);
            v += __shfl_xor(v, 32);
            if (lane < 16) {
                if (ngg == 0 && wv == 0) v += fcb[0];
                atomicAdd(out + m0 + lane, v);
            }
        }
    }
}

extern "C" void kernel_launch(void* const* d_in, const int* in_sizes, int n_in,
                              void* d_out, int out_size, void* d_ws, size_t ws_size,
                              hipStream_t stream)
{
    const float* x    = (const float*)d_in[0];
    const float* Wax0 = (const float*)d_in[1];
    const float* Uas0 = (const float*)d_in[2];
    const float* ba0  = (const float*)d_in[3];
    const float* Wih0 = (const float*)d_in[4];
    const float* Whh0 = (const float*)d_in[5];
    const float* bh0  = (const float*)d_in[6];
    const float* Wax1 = (const float*)d_in[7];
    const float* Uas1 = (const float*)d_in[8];
    const float* ba1  = (const float*)d_in[9];
    const float* Wih1 = (const float*)d_in[10];
    const float* Whh1 = (const float*)d_in[11];
    const float* bh1  = (const float*)d_in[12];
    const float* fcW  = (const float*)d_in[13];
    const float* fcb  = (const float*)d_in[14];
    float* out = (float*)d_out;

    char* ws = (char*)d_ws;
    u16* s0b = (u16*)(ws + S0_OFF);
    u16* s1b = (u16*)(ws + S1_OFF);
    u16* h0r = (u16*)(ws + H0_OFF);
    unsigned* flags = (unsigned*)(ws + FL_OFF);
    u16* wbase = (u16*)(ws + W_OFF);
    u16* wUas0 = wbase + 0 * 1048576;
    u16* wWhh0 = wbase + 1 * 1048576;
    u16* wWax1 = wbase + 2 * 1048576;
    u16* wUas1 = wbase + 3 * 1048576;
    u16* wWih1 = wbase + 4 * 1048576;
    u16* wWhh1 = wbase + 5 * 1048576;
    u16* wWax0 = wbase + 6 * 1048576;
    u16* wWih0 = wbase + 6 * 1048576 + 262144;

    hipMemsetAsync(d_ws, 0, W_OFF, stream);
    hipMemsetAsync(d_out, 0, (size_t)out_size * sizeof(float), stream);

    conv_weights<<<dim3(1024), dim3(256), 0, stream>>>(
        Uas0, Whh0, Wax1, Uas1, Wih1, Whh1, Wax0, Wih0, wbase);

    alphat_mfma<<<dim3(256), dim3(NTHR), 0, stream>>>(
        x, wUas0, wWhh0, wWax1, wUas1, wWih1, wWhh1, wWax0, wWih0,
        ba0, bh0, ba1, bh1, fcW, fcb, out, s0b, s1b, h0r, flags);
}

// Round 18
// 10323.199 us; speedup vs baseline: 1.1432x; 1.1214x over previous
//
#include <hip/hip_runtime.h>

// AlphatRNN B=128,T=512,D=256,H=1024,L=2,O=1 — bf16 MFMA persistent kernel, R18.
// R18 = R14 CHAMPION RESTORED (10.3ms, passing). Two WG pools (256 WGs total):
// blocks 0-127 = layer-0 engine (B chain, 1 exchange/step), blocks 128-255 =
// layer-1 engine (C+D, 1 serial exchange/step). WG tile 16x64 (4 n-tiles/wave,
// 8 K-eighth waves, dedup'd state reads); 16-WG sync groups; h0 via 32-step
// ring (8MB); monotonic 64B-padded producer flags. R15/R16/R17 perturbations
// (sync slimming, reg-weights, serial hoists) all regressed ~1.3ms -> this
// schedule is the measured optimum of the design family.

typedef unsigned short u16;
typedef unsigned long long u64;
typedef __attribute__((ext_vector_type(8))) short short8;
typedef __attribute__((ext_vector_type(4))) float f32x4;

#define NB   128
#define TT   512
#define DD   256
#define HH   1024
#define NTHR 512
#define SPAN (NB * HH)
#define RING 32
#define GS   16

// ---- ws layout (bytes) ----
#define S0_OFF  0u          // bf16 [2][128][1024] s0 parity
#define S1_OFF  524288u     // bf16 [2][128][1024] s1 parity
#define H0_OFF  1048576u    // bf16 [RING][128][1024] = 8 MB h0 ring
#define FL_OFF  9437184u    // fB/fC/fD: 3 x [8 mg][16 wgl] x 64 B = 24 KB
#define W_OFF   9486336u    // bf16 weights: 6x[1024][1024], then [1024][256]x2
#define NBIG    6291456u

__device__ __forceinline__ u16 f2bf(float f) {
    unsigned u = __builtin_bit_cast(unsigned, f);
    return (u16)((u + 0x7fffu + ((u >> 16) & 1u)) >> 16);
}
__device__ __forceinline__ u64 agent_load64(const u64* p) {
    return __hip_atomic_load(p, __ATOMIC_RELAXED, __HIP_MEMORY_SCOPE_AGENT);
}
__device__ __forceinline__ void agent_store64(u64* p, u64 v) {
    __hip_atomic_store(p, v, __ATOMIC_RELAXED, __HIP_MEMORY_SCOPE_AGENT);
}

// flag set: __syncthreads drains every wave's sc1 stores (compiler emits
// vmcnt(0) before s_barrier), then tid0 release-stores the step value.
__device__ __forceinline__ void flag_set(unsigned* f, int wgl, unsigned val, int tid)
{
    __syncthreads();
    if (tid == 0)
        __hip_atomic_store(f + wgl * 16, val, __ATOMIC_RELEASE,
                           __HIP_MEMORY_SCOPE_AGENT);
}
// consumer: lanes 0..15 (wave 0) poll the 16 group flags in parallel.
__device__ __forceinline__ void flag_wait(unsigned* f, unsigned val, int tid)
{
    if (tid < GS)
        while (__hip_atomic_load(f + tid * 16, __ATOMIC_RELAXED,
                                 __HIP_MEMORY_SCOPE_AGENT) < val)
            __builtin_amdgcn_s_sleep(1);
    __syncthreads();
}

// state frags, one K-EIGHTH (128 k): lane(lrow,lkg) reads row m0+lrow,
// k = wv*128 + s*32 + lkg*8, s=0..3. sc1 loads from a published span.
__device__ __forceinline__ void load_frags(short8* fr, const u16* base,
                                           int row, int wv, int lkg)
{
    const u16* sp = base + ((size_t)row << 10) + wv * 128 + lkg * 8;
    #pragma unroll
    for (int s = 0; s < 4; ++s) {
        union { short8 v; u64 q[2]; } u_;
        u_.q[0] = agent_load64((const u64*)(sp + s * 32));
        u_.q[1] = agent_load64((const u64*)(sp + s * 32 + 4));
        fr[s] = u_.v;
    }
}

// a[nt] += W[n0+nt*16+lrow, K-eighth] (x) S(frags), swapped operands
// (D rows = W rows = H-cols, D cols = batch). 16 mfma per call.
__device__ __forceinline__ void mm4(f32x4* a, const short8* fr, const u16* W,
                                    int n0, int lrow, int wv, int lkg)
{
    #pragma unroll
    for (int nt = 0; nt < 4; ++nt) {
        const u16* wp = W + ((size_t)(n0 + nt * 16 + lrow) << 10) + wv * 128 + lkg * 8;
        #pragma unroll
        for (int s = 0; s < 4; ++s)
            a[nt] = __builtin_amdgcn_mfma_f32_16x16x32_bf16(
                *(const short8*)(wp + s * 32), fr[s], a[nt], 0, 0, 0);
    }
}

// a[nt] += Wx[n0+nt*16+lrow, K-eighth of 256] (x) x_row(fp32->bf16), swapped.
__device__ __forceinline__ void mmx4(f32x4* a, const float* xrow, const u16* W,
                                     int n0, int lrow, int wv, int lkg)
{
    const float* p = xrow + wv * 32 + lkg * 8;
    float4 A = *(const float4*)p;
    float4 B = *(const float4*)(p + 4);
    short8 v;
    v[0]=(short)f2bf(A.x); v[1]=(short)f2bf(A.y); v[2]=(short)f2bf(A.z); v[3]=(short)f2bf(A.w);
    v[4]=(short)f2bf(B.x); v[5]=(short)f2bf(B.y); v[6]=(short)f2bf(B.z); v[7]=(short)f2bf(B.w);
    #pragma unroll
    for (int nt = 0; nt < 4; ++nt) {
        const u16* wp = W + ((size_t)(n0 + nt * 16 + lrow) << 8) + wv * 32 + lkg * 8;
        a[nt] = __builtin_amdgcn_mfma_f32_16x16x32_bf16(
            *(const short8*)wp, v, a[nt], 0, 0, 0);
    }
}

// 32KB reduce plane [comp][nt][wave][lane]: 4B lane stride, conflict-free.
__device__ __forceinline__ void red_put(float (*red)[4][8][64], const f32x4* a,
                                        int wv, int lane)
{
    #pragma unroll
    for (int nt = 0; nt < 4; ++nt)
        #pragma unroll
        for (int c = 0; c < 4; ++c) red[c][nt][wv][lane] = a[nt][c];
}
__device__ __forceinline__ f32x4 red_get(float (*red)[4][8][64], int nt, int lane)
{
    f32x4 v = {0.f, 0.f, 0.f, 0.f};
    #pragma unroll
    for (int j = 0; j < 8; ++j)
        #pragma unroll
        for (int c = 0; c < 4; ++c) v[c] += red[c][nt][j][lane];
    return v;
}

__device__ __forceinline__ u64 pack4(float a, float b, float c, float d)
{
    return (u64)f2bf(a) | ((u64)f2bf(b) << 16) | ((u64)f2bf(c) << 32)
         | ((u64)f2bf(d) << 48);
}

__global__ void conv_weights(const float* Uas0, const float* Whh0, const float* Wax1,
                             const float* Uas1, const float* Wih1, const float* Whh1,
                             const float* Wax0, const float* Wih0, u16* dst)
{
    for (size_t i = (size_t)blockIdx.x * blockDim.x + threadIdx.x; i < 6815744u;
         i += (size_t)gridDim.x * blockDim.x) {
        const float* src; size_t off;
        if (i < NBIG) {
            int seg = (int)(i >> 20); off = i & 1048575u;
            src = seg == 0 ? Uas0 : seg == 1 ? Whh0 : seg == 2 ? Wax1
                : seg == 3 ? Uas1 : seg == 4 ? Wih1 : Whh1;
        } else {
            size_t j = i - NBIG; off = j & 262143u;
            src = (j >> 18) ? Wih0 : Wax0;
        }
        dst[i] = f2bf(src[off]);
    }
}

extern "C" __global__ void __launch_bounds__(NTHR, 1)
alphat_mfma(const float* __restrict__ x,
            const u16* __restrict__ wUas0, const u16* __restrict__ wWhh0,
            const u16* __restrict__ wWax1, const u16* __restrict__ wUas1,
            const u16* __restrict__ wWih1, const u16* __restrict__ wWhh1,
            const u16* __restrict__ wWax0, const u16* __restrict__ wWih0,
            const float* __restrict__ ba0, const float* __restrict__ bh0,
            const float* __restrict__ ba1, const float* __restrict__ bh1,
            const float* __restrict__ fcW, const float* __restrict__ fcb,
            float* __restrict__ out,
            u16* s0b, u16* s1b, u16* h0r, unsigned* flags)
{
    __shared__ float red[4][4][8][64];   // 32 KB, one plane set (serial reuse)

    const int tid  = threadIdx.x;
    const int wv   = tid >> 6;           // K-eighth; waves 0-3 own n-tiles 0-3
    const int lane = tid & 63;
    const int lrow = lane & 15;
    const int lkg  = lane >> 4;

    const bool isL0 = (blockIdx.x < 128);
    const int wg  = isL0 ? blockIdx.x : (blockIdx.x - 128);
    const int ngg = (wg & 7) * 2 + ((wg >> 3) & 1);   // same-XCD pairs share cols
    const int mg  = wg >> 4;             // sync group = batch row-block
    const int wgl = wg & 15;
    const int m0  = mg * 16;
    const int n0  = ngg * 64;

    unsigned* fB = flags + (size_t)mg * 256;          // [16] x 16 dwords
    unsigned* fC = flags + 2048 + (size_t)mg * 256;
    unsigned* fD = flags + 4096 + (size_t)mg * 256;

    const int arow = m0 + lrow;
    const bool own = (wv < 4);
    const int nb   = n0 + (wv & 3) * 16 + lkg * 4;    // owner cols (wv<4)

    const f32x4 zf = {0.f, 0.f, 0.f, 0.f};
    const size_t HIDB = NB, SMOB = NB + 2 * (size_t)SPAN;

    if (isL0) {
        // ================== layer-0 pool: B chain (1 exchange/step) ==========
        float4 vba0 = {0,0,0,0}, vbh0 = {0,0,0,0};
        if (own) { vba0 = *(const float4*)(ba0 + nb); vbh0 = *(const float4*)(bh0 + nb); }
        float h0l[4] = {0,0,0,0}, s0l[4] = {0,0,0,0};

        short8 frags[4];
        #pragma unroll
        for (int s = 0; s < 4; ++s)
            #pragma unroll
            for (int i = 0; i < 8; ++i) frags[s][i] = 0;
        const float* xbase = x + (size_t)arow * (TT * DD);
        f32x4 pBx[4], pAx[4];
        #pragma unroll
        for (int nt = 0; nt < 4; ++nt) { pBx[nt] = zf; pAx[nt] = zf; }
        mmx4(pBx, xbase + 0 * DD, wWih0, n0, lrow, wv, lkg);   // Wih0 x_0
        mmx4(pAx, xbase + 1 * DD, wWax0, n0, lrow, wv, lkg);   // Wax0 x_1

        for (int t = 0; t < TT; ++t) {
            u16* h0cur = h0r + (size_t)(t & (RING - 1)) * SPAN;
            u16* s0nxt = s0b + ((t + 1) & 1) * SPAN;

            // ring WAR: overwriting slot holds h0(t-32); C(t-32) readers done
            // iff fC >= t-31 (fC set after C's fh loads).
            if (t >= RING) flag_wait(fC, (unsigned)(t - RING + 1), tid);

            f32x4 acc[4], pA[4];
            #pragma unroll
            for (int nt = 0; nt < 4; ++nt) { acc[nt] = pBx[nt]; pA[nt] = pAx[nt]; }
            mm4(acc, frags, wWhh0, n0, lrow, wv, lkg);
            mm4(pA,  frags, wUas0, n0, lrow, wv, lkg);

            // two sequential reduces through one 32KB plane
            red_put(red, acc, wv, lane);
            __syncthreads();
            f32x4 hsum = zf;
            if (own) hsum = red_get(red, wv, lane);
            __syncthreads();
            red_put(red, pA, wv, lane);
            __syncthreads();
            if (own) {
                f32x4 asum = red_get(red, wv, lane);
                float hb[4];
                #pragma unroll
                for (int r = 0; r < 4; ++r) {
                    hb[r] = tanhf(hsum[r] + ((const float*)&vbh0)[r]);
                    h0l[r] = hb[r];
                }
                agent_store64((u64*)(h0cur + (size_t)(m0 + lrow) * HH + nb),
                              pack4(hb[0], hb[1], hb[2], hb[3]));
                if (t + 1 < TT) {
                    float sb[4];
                    #pragma unroll
                    for (int r = 0; r < 4; ++r) {
                        float al = 1.f / (1.f + __expf(-(asum[r] + ((const float*)&vba0)[r])));
                        sb[r] = al * hb[r] + (1.f - al) * s0l[r];
                        s0l[r] = sb[r];
                    }
                    agent_store64((u64*)(s0nxt + (size_t)(m0 + lrow) * HH + nb),
                                  pack4(sb[0], sb[1], sb[2], sb[3]));
                }
            }
            flag_set(fB, wgl, (unsigned)(t + 1), tid);

            if (t + 1 < TT) {
                // fill the fB-wait window with next x partials
                #pragma unroll
                for (int nt = 0; nt < 4; ++nt) pBx[nt] = zf;
                mmx4(pBx, xbase + (size_t)(t + 1) * DD, wWih0, n0, lrow, wv, lkg);
                if (t + 2 < TT) {
                    #pragma unroll
                    for (int nt = 0; nt < 4; ++nt) pAx[nt] = zf;
                    mmx4(pAx, xbase + (size_t)(t + 2) * DD, wWax0, n0, lrow, wv, lkg);
                }
                flag_wait(fB, (unsigned)(t + 1), tid);   // all s0(t+1) published
                load_frags(frags, s0nxt, arow, wv, lkg);
                // s0 parity WAR: B(t+1) overwrites s0[t&1]=s0(t-1)... writer
                // passed fB(t+1): all WGs finished B(t) which consumed s0(t-1)
                // frags loaded before their fB(t) set. Safe.
            }
        }
        if (own) {
            const size_t o = (size_t)(m0 + lrow) * HH + nb;
            *(float4*)(out + HIDB + o) = make_float4(h0l[0], h0l[1], h0l[2], h0l[3]);
            *(float4*)(out + SMOB + o) = make_float4(s0l[0], s0l[1], s0l[2], s0l[3]);
        }
    } else {
        // ================== layer-1 pool: C+D (1 serial exchange/step) =======
        float4 vba1 = {0,0,0,0}, vbh1 = {0,0,0,0};
        if (own) { vba1 = *(const float4*)(ba1 + nb); vbh1 = *(const float4*)(bh1 + nb); }
        float h1l[4] = {0,0,0,0}, s1l[4] = {0,0,0,0};
        f32x4 pC1[4];
        #pragma unroll
        for (int nt = 0; nt < 4; ++nt) pC1[nt] = zf;   // Uas1 s1(-1) = 0

        for (int t = 0; t < TT; ++t) {
            u16* h0cur = h0r + (size_t)(t & (RING - 1)) * SPAN;
            u16* s1cur = s1b + (t & 1) * SPAN;

            // s1 parity WAR: C(t) overwrites s1(t-2); D(t-2) readers done iff
            // fD >= t-1 (fD set after D's fs1 loads+mfma).
            if (t >= 2) flag_wait(fD, (unsigned)(t - 1), tid);

            // h0(t) from ring; producer runs ahead -> usually pre-satisfied.
            flag_wait(fB, (unsigned)(t + 1), tid);
            short8 fh[4];
            load_frags(fh, h0cur, arow, wv, lkg);

            // ---- C: alpha1(t), s1(t) publish ----
            f32x4 c[4];
            #pragma unroll
            for (int nt = 0; nt < 4; ++nt) c[nt] = pC1[nt];
            mm4(c, fh, wWax1, n0, lrow, wv, lkg);
            red_put(red, c, wv, lane);
            __syncthreads();
            if (own) {
                f32x4 csum = red_get(red, wv, lane);
                float sb[4];
                #pragma unroll
                for (int r = 0; r < 4; ++r) {
                    float al = 1.f / (1.f + __expf(-(csum[r] + ((const float*)&vba1)[r])));
                    sb[r] = al * h1l[r] + (1.f - al) * s1l[r];
                    s1l[r] = sb[r];
                }
                agent_store64((u64*)(s1cur + (size_t)(m0 + lrow) * HH + nb),
                              pack4(sb[0], sb[1], sb[2], sb[3]));
            }
            flag_set(fC, wgl, (unsigned)(t + 1), tid);

            // hide pD1 = Wih1 h0 inside the fC exchange window (fh in regs)
            f32x4 pD1[4];
            #pragma unroll
            for (int nt = 0; nt < 4; ++nt) pD1[nt] = zf;
            mm4(pD1, fh, wWih1, n0, lrow, wv, lkg);

            // ---- D: wait s1(t); h1(t); pC1 for C(t+1) ----
            flag_wait(fC, (unsigned)(t + 1), tid);
            short8 fs1[4];
            load_frags(fs1, s1cur, arow, wv, lkg);
            mm4(pD1, fs1, wWhh1, n0, lrow, wv, lkg);
            #pragma unroll
            for (int nt = 0; nt < 4; ++nt) pC1[nt] = zf;
            mm4(pC1, fs1, wUas1, n0, lrow, wv, lkg);
            red_put(red, pD1, wv, lane);
            __syncthreads();
            if (own) {
                f32x4 dsum = red_get(red, wv, lane);
                #pragma unroll
                for (int r = 0; r < 4; ++r)
                    h1l[r] = tanhf(dsum[r] + ((const float*)&vbh1)[r]);
            }
            flag_set(fD, wgl, (unsigned)(t + 1), tid);
        }
        if (own) {
            const size_t o = (size_t)(m0 + lrow) * HH + nb;
            *(float4*)(out + HIDB + SPAN + o) = make_float4(h1l[0], h1l[1], h1l[2], h1l[3]);
            *(float4*)(out + SMOB + SPAN + o) = make_float4(s1l[0], s1l[1], s1l[2], s1l[3]);

            const float4 w4 = *(const float4*)(fcW + nb);
            float v = h1l[0] * w4.x + h1l[1] * w4.y + h1l[2] * w4.z + h1l[3] * w4.w;
            v += __shfl_xor(v, 16);
            v += __shfl_xor(v, 32);
            if (lane < 16) {
                if (ngg == 0 && wv == 0) v += fcb[0];
                atomicAdd(out + m0 + lane, v);
            }
        }
    }
}

extern "C" void kernel_launch(void* const* d_in, const int* in_sizes, int n_in,
                              void* d_out, int out_size, void* d_ws, size_t ws_size,
                              hipStream_t stream)
{
    const float* x    = (const float*)d_in[0];
    const float* Wax0 = (const float*)d_in[1];
    const float* Uas0 = (const float*)d_in[2];
    const float* ba0  = (const float*)d_in[3];
    const float* Wih0 = (const float*)d_in[4];
    const float* Whh0 = (const float*)d_in[5];
    const float* bh0  = (const float*)d_in[6];
    const float* Wax1 = (const float*)d_in[7];
    const float* Uas1 = (const float*)d_in[8];
    const float* ba1  = (const float*)d_in[9];
    const float* Wih1 = (const float*)d_in[10];
    const float* Whh1 = (const float*)d_in[11];
    const float* bh1  = (const float*)d_in[12];
    const float* fcW  = (const float*)d_in[13];
    const float* fcb  = (const float*)d_in[14];
    float* out = (float*)d_out;

    char* ws = (char*)d_ws;
    u16* s0b = (u16*)(ws + S0_OFF);
    u16* s1b = (u16*)(ws + S1_OFF);
    u16* h0r = (u16*)(ws + H0_OFF);
    unsigned* flags = (unsigned*)(ws + FL_OFF);
    u16* wbase = (u16*)(ws + W_OFF);
    u16* wUas0 = wbase + 0 * 1048576;
    u16* wWhh0 = wbase + 1 * 1048576;
    u16* wWax1 = wbase + 2 * 1048576;
    u16* wUas1 = wbase + 3 * 1048576;
    u16* wWih1 = wbase + 4 * 1048576;
    u16* wWhh1 = wbase + 5 * 1048576;
    u16* wWax0 = wbase + 6 * 1048576;
    u16* wWih0 = wbase + 6 * 1048576 + 262144;

    // zero states + ring + flags + output (out accumulated via atomics)
    hipMemsetAsync(d_ws, 0, W_OFF, stream);
    hipMemsetAsync(d_out, 0, (size_t)out_size * sizeof(float), stream);

    conv_weights<<<dim3(1024), dim3(256), 0, stream>>>(
        Uas0, Whh0, Wax1, Uas1, Wih1, Whh1, Wax0, Wih0, wbase);

    alphat_mfma<<<dim3(256), dim3(NTHR), 0, stream>>>(
        x, wUas0, wWhh0, wWax1, wUas1, wWih1, wWhh1, wWax0, wWih0,
        ba0, bh0, ba1, bh1, fcW, fcb, out, s0b, s1b, h0r, flags);
}